// Round 13
// baseline (785.769 us; speedup 1.0000x reference)
//
#include <hip/hip_runtime.h>
#include <hip/hip_bf16.h>

// Dims
#define BB 32
#define TT 64
#define HH 512
#define EE 512
#define VV 32000

typedef float f32x4 __attribute__((ext_vector_type(4)));
typedef float f32x16 __attribute__((ext_vector_type(16)));
typedef __bf16 bf16x8 __attribute__((ext_vector_type(8)));
typedef unsigned short u16x8 __attribute__((ext_vector_type(8)));

static __device__ __forceinline__ unsigned short f2bf(float f) {
  unsigned int u = __builtin_bit_cast(unsigned int, f);
  u += 0x7fffu + ((u >> 16) & 1u);   // RNE; inputs are finite
  return (unsigned short)(u >> 16);
}

static __device__ __forceinline__ void gload16(const void* g, void* l) {
  __builtin_amdgcn_global_load_lds(
      (const __attribute__((address_space(1))) void*)g,
      (__attribute__((address_space(3))) void*)l, 16, 0, 0);
}

// ---- fp32 -> bf16 bulk convert (8 elems/thread) ----
__global__ __launch_bounds__(256) void k_cvt_bf16(const float* __restrict__ in,
                                                  unsigned short* __restrict__ out,
                                                  int n8) {
  int tid = blockIdx.x * 256 + threadIdx.x;
  if (tid >= n8) return;
  int idx = tid * 8;
  float4 a = *(const float4*)(in + idx);
  float4 b = *(const float4*)(in + idx + 4);
  u16x8 o;
  o[0] = f2bf(a.x); o[1] = f2bf(a.y); o[2] = f2bf(a.z); o[3] = f2bf(a.w);
  o[4] = f2bf(b.x); o[5] = f2bf(b.y); o[6] = f2bf(b.z); o[7] = f2bf(b.w);
  *(u16x8*)(out + idx) = o;
}

// ---- fp32 [K][M] -> bf16 [M][K] transpose-convert (32x32 tiles) ----
__global__ __launch_bounds__(256) void k_trcvt(const float* __restrict__ in,  // [512][512]
                                               unsigned short* __restrict__ out) {
  __shared__ float tile[32][33];
  const int tx = threadIdx.x & 31, ty = threadIdx.x >> 5;   // 32x8
  const int k0 = blockIdx.x * 32, m0 = blockIdx.y * 32;
#pragma unroll
  for (int r = 0; r < 4; ++r)
    tile[ty + r * 8][tx] = in[(size_t)(k0 + ty + r * 8) * 512 + m0 + tx];
  __syncthreads();
#pragma unroll
  for (int r = 0; r < 4; ++r)
    out[(size_t)(m0 + ty + r * 8) * 512 + k0 + tx] = f2bf(tile[tx][ty + r * 8]);
}

// ---- embedding gather -> bf16, layout [t*B+b][E] ----
__global__ __launch_bounds__(256) void k_emb(const int* __restrict__ seq,
                                             const float* __restrict__ emb,
                                             unsigned short* __restrict__ out) {
  int tid = blockIdx.x * 256 + threadIdx.x;   // 2048*512/8 = 131072 threads
  int idx = tid * 8;
  int m = idx >> 9;          // t*32 + b
  int e0 = idx & 511;
  int t = m >> 5, b = m & 31;
  int s = seq[b * TT + t];
  const float* src = emb + (size_t)s * EE + e0;
  float4 a = *(const float4*)(src);
  float4 c = *(const float4*)(src + 4);
  u16x8 o;
  o[0] = f2bf(a.x); o[1] = f2bf(a.y); o[2] = f2bf(a.z); o[3] = f2bf(a.w);
  o[4] = f2bf(c.x); o[5] = f2bf(c.y); o[6] = f2bf(c.z); o[7] = f2bf(c.w);
  *(u16x8*)(out + m * EE + e0) = o;
}

__global__ __launch_bounds__(256) void k_beff(const float* __restrict__ W_out,
                                              const float* __restrict__ b_in,
                                              const float* __restrict__ b_out,
                                              float* __restrict__ b_eff) {
  int i = blockIdx.x * 256 + threadIdx.x;
  if (i >= HH) return;
  float acc = b_out[i];
  for (int k = 0; k < HH; ++k) acc += W_out[i * 1024 + k] * b_in[k];
  b_eff[i] = acc;
}

// ---- bf16 MFMA GEMM (m97-style): C[M][N] = A[M][K]*Bm[N][K]^T (+biases,+addend) ----
// Used for the small GEMMs (weff, xproj). Linear LDS [128][32], gload_lds staging.
__global__ __launch_bounds__(256) void k_gemm(const unsigned short* __restrict__ A, int lda,
                                              const unsigned short* __restrict__ Bm, int ldb,
                                              float* __restrict__ C, int ldc,
                                              const float* __restrict__ bias1,
                                              const float* __restrict__ bias2,
                                              const float* __restrict__ biasR1,
                                              const float* __restrict__ biasR2,
                                              const float* __restrict__ Cadd, int ldadd,
                                              int K, int m_panels) {
  __shared__ unsigned short As[128 * 32];
  __shared__ unsigned short Bs[128 * 32];
  const int tx = threadIdx.x;
  const int lane = tx & 63, w = tx >> 6;
  const int wrow = (w >> 1) * 64, wcol = (w & 1) * 64;
  const int l15 = lane & 15, lk = lane >> 4;
  const int nb = gridDim.x;
  const int swz = (blockIdx.x & 7) * (nb >> 3) + (blockIdx.x >> 3);
  const int m0 = (swz % m_panels) * 128, n0 = (swz / m_panels) * 128;
  const int r_lane = lane >> 2;          // row within a 16-row chunk
  const int k_lane = (lane & 3) * 8;     // k element offset within BK=32
  f32x4 acc[4][4] = {};
  for (int k0 = 0; k0 < K; k0 += 32) {
#pragma unroll
    for (int h = 0; h < 2; ++h) {
      int r0 = w * 32 + h * 16;
      gload16(A + (size_t)(m0 + r0 + r_lane) * lda + k0 + k_lane, &As[r0 * 32]);
      gload16(Bm + (size_t)(n0 + r0 + r_lane) * ldb + k0 + k_lane, &Bs[r0 * 32]);
    }
    asm volatile("s_waitcnt vmcnt(0)" ::: "memory");
    __syncthreads();
    bf16x8 av[4], bv[4];
#pragma unroll
    for (int mi = 0; mi < 4; ++mi)
      av[mi] = __builtin_bit_cast(bf16x8, *(const int4*)(&As[(wrow + mi * 16 + l15) * 32 + lk * 8]));
#pragma unroll
    for (int ni = 0; ni < 4; ++ni)
      bv[ni] = __builtin_bit_cast(bf16x8, *(const int4*)(&Bs[(wcol + ni * 16 + l15) * 32 + lk * 8]));
#pragma unroll
    for (int mi = 0; mi < 4; ++mi)
#pragma unroll
      for (int ni = 0; ni < 4; ++ni)
        acc[mi][ni] = __builtin_amdgcn_mfma_f32_16x16x32_bf16(av[mi], bv[ni], acc[mi][ni], 0, 0, 0);
    __syncthreads();
  }
#pragma unroll
  for (int mi = 0; mi < 4; ++mi) {
#pragma unroll
    for (int ni = 0; ni < 4; ++ni) {
      int row = m0 + wrow + mi * 16 + lk * 4;
      int col = n0 + wcol + ni * 16 + l15;
      float bb = 0.f;
      if (bias1) bb += bias1[col];
      if (bias2) bb += bias2[col];
#pragma unroll
      for (int q = 0; q < 4; ++q) {
        float bR = 0.f;
        if (biasR1) bR += biasR1[row + q];
        if (biasR2) bR += biasR2[row + q];
        float ad = Cadd ? Cadd[(size_t)(row + q) * ldadd + col] : 0.f;
        C[(size_t)(row + q) * ldc + col] = acc[mi][ni][q] + bb + bR + ad;
      }
    }
  }
}

// ---- logits GEMM v3: 256x256 tile, 8 waves, BK=64, dbuf LDS + counted vmcnt ----
// C[2048][32000] = A[2048][512] * B[32000][512]^T + biasN.
// A is read DIRECTLY from outs_e (bf16 [t][b][512]) with the (b*64+t)->(t*32+b)
// source-row permutation folded into the per-lane global address (k_tr removed).
// XOR swizzle on the global source chunk + ds_read address (both-sides rule).
__global__ __launch_bounds__(512) void k_gemm2(const unsigned short* __restrict__ Aouts,
                                               const unsigned short* __restrict__ Bm,
                                               float* __restrict__ C,
                                               const float* __restrict__ biasN) {
  __shared__ unsigned short As[2][256 * 64];   // 2 x 32 KB
  __shared__ unsigned short Bs[2][256 * 64];   // 2 x 32 KB
  const int tx = threadIdx.x;
  const int lane = tx & 63, w = tx >> 6;        // 8 waves
  const int wrow = (w >> 2) * 128, wcol = (w & 3) * 64;
  const int l15 = lane & 15, lk = lane >> 4;
  const int nb = gridDim.x;                     // 1000
  const int swz = (blockIdx.x & 7) * (nb >> 3) + (blockIdx.x >> 3);
  const int m0 = (swz & 7) * 256, n0 = (swz >> 3) * 256;
  const int lr = lane >> 3, lc = lane & 7;      // staging: row-in-8group, 16B chunk
  f32x4 acc[8][4] = {};

  auto stage = [&](int buf, int k0) {           // 8 gload16 per wave
#pragma unroll
    for (int i = 0; i < 4; ++i) {
      int row = w * 32 + i * 8 + lr;            // A tile row 0..255
      int ar = m0 + row;                        // logical row b*64+t
      const unsigned short* srcA =
          Aouts + (size_t)((ar & 63) * 32 + (ar >> 6)) * 512 + k0 + ((lc ^ (row & 7)) * 8);
      gload16(srcA, &As[buf][(w * 32 + i * 8) * 64]);
    }
#pragma unroll
    for (int i = 0; i < 4; ++i) {
      int row = w * 32 + i * 8 + lr;
      gload16(Bm + (size_t)(n0 + row) * 512 + k0 + ((lc ^ (row & 7)) * 8),
              &Bs[buf][(w * 32 + i * 8) * 64]);
    }
  };

  stage(0, 0);
  for (int ks = 0; ks < 8; ++ks) {
    const int cur = ks & 1;
    if (ks < 7) {
      stage(cur ^ 1, (ks + 1) * 64);
      asm volatile("s_waitcnt vmcnt(8)" ::: "memory");   // this wave's cur-buf loads done
    } else {
      asm volatile("s_waitcnt vmcnt(0)" ::: "memory");
    }
    __syncthreads();   // every wave drained its cur-buf loads before arriving
    const char* Ab = (const char*)As[cur];
    const char* Bb = (const char*)Bs[cur];
#pragma unroll
    for (int kk = 0; kk < 2; ++kk) {            // two K32-chunks
      bf16x8 av[8], bv[4];
#pragma unroll
      for (int mi = 0; mi < 8; ++mi) {
        int row = wrow + mi * 16 + l15;
        int c = kk * 4 + lk;
        av[mi] = __builtin_bit_cast(bf16x8,
            *(const int4*)(Ab + row * 128 + ((c ^ (row & 7)) << 4)));
      }
#pragma unroll
      for (int ni = 0; ni < 4; ++ni) {
        int row = wcol + ni * 16 + l15;
        int c = kk * 4 + lk;
        bv[ni] = __builtin_bit_cast(bf16x8,
            *(const int4*)(Bb + row * 128 + ((c ^ (row & 7)) << 4)));
      }
#pragma unroll
      for (int mi = 0; mi < 8; ++mi)
#pragma unroll
        for (int ni = 0; ni < 4; ++ni)
          acc[mi][ni] = __builtin_amdgcn_mfma_f32_16x16x32_bf16(av[mi], bv[ni], acc[mi][ni], 0, 0, 0);
    }
    __syncthreads();   // all waves done reading buf[cur] before next stage overwrites it
  }
#pragma unroll
  for (int mi = 0; mi < 8; ++mi) {
#pragma unroll
    for (int ni = 0; ni < 4; ++ni) {
      int row = m0 + wrow + mi * 16 + lk * 4;
      int col = n0 + wcol + ni * 16 + l15;
      float bb = biasN[col];
#pragma unroll
      for (int q = 0; q < 4; ++q)
        __builtin_nontemporal_store(acc[mi][ni][q] + bb,
                                    &C[(size_t)(row + q) * 32000 + col]);
    }
  }
}

// ---- fence-free grid barrier for 64 blocks (r6-proven, WITH sleep) ----
static __device__ __forceinline__ void gbar(unsigned* __restrict__ bar, unsigned gen) {
  __syncthreads();
  if (threadIdx.x == 0) {
    asm volatile("s_waitcnt vmcnt(0)" ::: "memory");
    __hip_atomic_store(&bar[blockIdx.x], gen, __ATOMIC_RELAXED, __HIP_MEMORY_SCOPE_AGENT);
  }
  if (threadIdx.x < 64) {
    while (__hip_atomic_load(&bar[threadIdx.x], __ATOMIC_RELAXED, __HIP_MEMORY_SCOPE_AGENT) < gen)
      __builtin_amdgcn_s_sleep(1);
  }
  __syncthreads();
  asm volatile("" ::: "memory");   // keep data loads below the spin
}

// ---- persistent MFMA recurrence: 64 blocks x 256 threads (4 waves), r6-proven ----
__global__ __launch_bounds__(256, 1) void k_recur(
    const float* __restrict__ xprojT,       // [2048][2048] fp32 (incl. b_ih+b_hh)
    const unsigned short* __restrict__ wih_b,  // [2048][1024] bf16
    const unsigned short* __restrict__ whh_b,  // [2048][512] bf16
    const unsigned short* __restrict__ weff_b, // [512][512] bf16
    const float* __restrict__ b_eff,        // [512]
    const float* __restrict__ enc_c,        // [32][512] fp32
    unsigned short* __restrict__ h_ext,     // [65][32][512] bf16; slab 0 = bf16(enc_h)
    unsigned short* __restrict__ outs_ext,  // [65][32][512] bf16; slab 0 zeroed
    unsigned* __restrict__ bar)
{
  __shared__ int4 Abuf4[4096];             // A[32][1024] bf16, XOR-swizzled (64 KB)
  __shared__ float red[4][32][32];         // cross-wave K-partials (16 KB)
  char* Abuf = (char*)Abuf4;

  const int tx = threadIdx.x;
  const int bid = blockIdx.x;
  const int i0 = bid * 8;
  const int w = tx >> 6, l = tx & 63;
  const int jl = l & 31;                   // MFMA operand row (gate-row local / batch)
  const int kh = (l >> 5) * 8;             // k sub-offset within a K16 tile
  const int u = tx >> 5, b = tx & 31;      // activation mapping: unit u (0..7), batch b

  // ---- one-time: weights into registers ----
  bf16x8 wg[16];
  {
    const int jg = (jl >> 3) * 512 + i0 + (jl & 7);   // global gate row
#pragma unroll
    for (int r = 0; r < 16; ++r) {
      int k0 = (w * 16 + r) * 16 + kh;
      const unsigned short* src = (k0 < 512)
          ? wih_b + (size_t)jg * 1024 + 512 + k0      // feed half of W_ih
          : whh_b + (size_t)jg * 512 + (k0 - 512);    // W_hh
      wg[r] = __builtin_bit_cast(bf16x8, *(const int4*)src);
    }
  }
  bf16x8 we[8];
  {
    const int wr = (bid >> 2) * 32 + jl;              // W_eff row (unit group)
#pragma unroll
    for (int r = 0; r < 8; ++r) {
      int k0 = (w * 8 + r) * 16 + kh;
      we[r] = __builtin_bit_cast(bf16x8, *(const int4*)(weff_b + (size_t)wr * 512 + k0));
    }
  }
  float c_reg = enc_c[b * 512 + i0 + u];
  const float be = b_eff[i0 + u];

  // ---- block-wide stage helpers (r6) ----
  auto stage = [&](const unsigned short* __restrict__ src, int half) {
#pragma unroll
    for (int rnd = 0; rnd < 8; ++rnd) {
      int id = rnd * 256 + tx;
      int row = id >> 6, c16 = id & 63;
      int4 v = *(const int4*)(src + (size_t)row * 512 + c16 * 8);
      int byte = (row * 2048 + half * 1024 + c16 * 16) ^ ((row & 7) << 4);
      *(int4*)(Abuf + byte) = v;
    }
  };
  auto afrag = [&](int ktile) -> bf16x8 {   // ktile in K16 units over full K=1024
    int byte = (jl * 2048 + ktile * 32 + (l >> 5) * 16) ^ ((jl & 7) << 4);
    return __builtin_bit_cast(bf16x8, *(const int4*)(Abuf + byte));
  };

  // initial stage: feed slab 0 (zeros) + h slab 0 (enc_h)
  stage(outs_ext, 0);
  stage(h_ext, 1);
  __syncthreads();

  unsigned gen = 1;
  for (int t = 0; t < 64; ++t) {
    // ================= phase 1: gates -> h_t+1 =================
    float xp[4];
#pragma unroll
    for (int g = 0; g < 4; ++g)
      xp[g] = xprojT[(size_t)(g * 512 + i0 + u) * 2048 + t * 32 + b];
    f32x16 acc = {};
#pragma unroll
    for (int r = 0; r < 16; ++r)
      acc = __builtin_amdgcn_mfma_f32_32x32x16_bf16(wg[r], afrag(w * 16 + r), acc, 0, 0, 0);
#pragma unroll
    for (int reg = 0; reg < 16; ++reg) {
      int row = (reg & 3) + 8 * (reg >> 2) + 4 * (l >> 5);
      red[w][row][jl] = acc[reg];
    }
    __syncthreads();
    {
      float g4[4];
#pragma unroll
      for (int g = 0; g < 4; ++g)
        g4[g] = red[0][g * 8 + u][b] + red[1][g * 8 + u][b]
              + red[2][g * 8 + u][b] + red[3][g * 8 + u][b] + xp[g];
      float si = 1.f / (1.f + __expf(-g4[0]));
      float sf = 1.f / (1.f + __expf(-g4[1]));
      float so = 1.f / (1.f + __expf(-g4[3]));
      float cn = sf * c_reg + si * tanhf(g4[2]);
      c_reg = cn;
      unsigned hb = f2bf(so * tanhf(cn));
      unsigned other = (unsigned)__shfl_down((int)hb, 32);
      if ((u & 1) == 0) {
        unsigned* h32 = (unsigned*)(h_ext + (size_t)(t + 1) * 16384);
        __hip_atomic_store(&h32[b * 256 + bid * 4 + (u >> 1)], hb | (other << 16),
                           __ATOMIC_RELAXED, __HIP_MEMORY_SCOPE_AGENT);
      }
    }
    gbar(bar, gen++);   // h_t+1 visible device-wide

    // ================= phase 2: feed = tanh(W_eff h + b_eff) =================
    stage(h_ext + (size_t)(t + 1) * 16384, 1);
    __syncthreads();
    f32x16 acc2 = {};
#pragma unroll
    for (int r = 0; r < 8; ++r)
      acc2 = __builtin_amdgcn_mfma_f32_32x32x16_bf16(we[r], afrag(32 + w * 8 + r), acc2, 0, 0, 0);
#pragma unroll
    for (int reg = 0; reg < 16; ++reg) {
      int row = (reg & 3) + 8 * (reg >> 2) + 4 * (l >> 5);
      red[w][row][jl] = acc2[reg];
    }
    __syncthreads();
    {
      int row = (bid & 3) * 8 + u;
      float s = red[0][row][b] + red[1][row][b] + red[2][row][b] + red[3][row][b] + be;
      unsigned ob = f2bf(tanhf(s));
      unsigned other = (unsigned)__shfl_down((int)ob, 32);
      if ((u & 1) == 0) {
        unsigned* o32 = (unsigned*)(outs_ext + (size_t)(t + 1) * 16384);
        __hip_atomic_store(&o32[b * 256 + bid * 4 + (u >> 1)], ob | (other << 16),
                           __ATOMIC_RELAXED, __HIP_MEMORY_SCOPE_AGENT);
      }
    }
    gbar(bar, gen++);   // feed visible device-wide

    if (t < 63) {       // stage next step's feed
      stage(outs_ext + (size_t)(t + 1) * 16384, 0);
      __syncthreads();
    }
  }
}

extern "C" void kernel_launch(void* const* d_in, const int* in_sizes, int n_in,
                              void* d_out, int out_size, void* d_ws, size_t ws_size,
                              hipStream_t stream) {
  const int*   seq      = (const int*)d_in[0];
  // d_in[1] = encoder_outputs: attention scores are dead code -> unused
  const float* enc_h    = (const float*)d_in[2];
  const float* enc_c    = (const float*)d_in[3];
  const float* emb      = (const float*)d_in[4];
  const float* W_ih     = (const float*)d_in[5];
  const float* b_ih     = (const float*)d_in[6];
  const float* W_hh     = (const float*)d_in[7];
  const float* b_hh     = (const float*)d_in[8];
  const float* W_inp    = (const float*)d_in[9];
  const float* b_inp    = (const float*)d_in[10];
  const float* W_outp   = (const float*)d_in[11];
  const float* b_outp   = (const float*)d_in[12];
  const float* W_final  = (const float*)d_in[13];
  const float* b_final  = (const float*)d_in[14];
  float* logits = (float*)d_out;

  char* ws = (char*)d_ws;
  size_t off = 0;
  auto alloc = [&](size_t bytes) {
    char* p = ws + off;
    off += (bytes + 255) & ~(size_t)255;
    return p;
  };
  unsigned short* wih_b  = (unsigned short*)alloc((size_t)2048 * 1024 * 2);
  unsigned short* whh_b  = (unsigned short*)alloc((size_t)2048 * 512 * 2);
  unsigned short* wfin_b = (unsigned short*)alloc((size_t)VV * HH * 2);
  unsigned short* weff_b = (unsigned short*)alloc((size_t)512 * 512 * 2);
  unsigned short* wout_b = (unsigned short*)alloc((size_t)512 * 1024 * 2);
  unsigned short* win_t  = (unsigned short*)alloc((size_t)512 * 512 * 2);
  unsigned short* emb_b  = (unsigned short*)alloc((size_t)2048 * 512 * 2);
  float* xprojT = (float*)alloc((size_t)2048 * 2048 * 4);
  float* W_eff  = (float*)alloc((size_t)512 * 512 * 4);
  float* b_eff  = (float*)alloc((size_t)512 * 4);
  unsigned short* h_ext  = (unsigned short*)alloc((size_t)65 * 32 * 512 * 2);
  unsigned short* outs_e = (unsigned short*)alloc((size_t)65 * 32 * 512 * 2);
  unsigned* bar = (unsigned*)alloc(4096);

  // per-call init (graph-safe)
  hipMemsetAsync(bar, 0, 4096, stream);
  hipMemsetAsync(outs_e, 0, (size_t)32 * 512 * 2, stream);   // feed for t=0 (bf16 zero)

  hipLaunchKernelGGL(k_cvt_bf16, dim3(1024), dim3(256), 0, stream, W_ih, wih_b, 2048 * 1024 / 8);
  hipLaunchKernelGGL(k_cvt_bf16, dim3(512), dim3(256), 0, stream, W_hh, whh_b, 2048 * 512 / 8);
  hipLaunchKernelGGL(k_cvt_bf16, dim3(8000), dim3(256), 0, stream, W_final, wfin_b, VV * HH / 8);
  hipLaunchKernelGGL(k_cvt_bf16, dim3(8), dim3(256), 0, stream, enc_h, h_ext, 32 * 512 / 8);
  hipLaunchKernelGGL(k_cvt_bf16, dim3(256), dim3(256), 0, stream, W_outp, wout_b, 512 * 1024 / 8);
  hipLaunchKernelGGL(k_trcvt, dim3(16, 16), dim3(256), 0, stream, W_inp, win_t);
  hipLaunchKernelGGL(k_emb, dim3(512), dim3(256), 0, stream, seq, emb, emb_b);
  hipLaunchKernelGGL(k_beff, dim3(2), dim3(256), 0, stream, W_outp, b_inp, b_outp, b_eff);

  // W_eff = W_out[:, :H] @ W_in + W_out[:, H:]  via MFMA
  hipLaunchKernelGGL(k_gemm, dim3(16), dim3(256), 0, stream,
                     wout_b, 1024, win_t, 512, W_eff, 512,
                     (const float*)nullptr, (const float*)nullptr,
                     (const float*)nullptr, (const float*)nullptr,
                     W_outp + 512, 1024, 512, 4);
  hipLaunchKernelGGL(k_cvt_bf16, dim3(128), dim3(256), 0, stream, W_eff, weff_b, 512 * 512 / 8);

  // xprojT[j][t*32+b] = W_ih[:, :E] @ emb^T + (b_ih + b_hh) per-row
  hipLaunchKernelGGL(k_gemm, dim3(256), dim3(256), 0, stream,
                     wih_b, 1024, emb_b, 512, xprojT, 2048,
                     (const float*)nullptr, (const float*)nullptr, b_ih, b_hh,
                     (const float*)nullptr, 0, 512, 16);

  // persistent MFMA recurrence: 64 blocks, all 64 steps, 2 barriers each
  hipLaunchKernelGGL(k_recur, dim3(64), dim3(256), 0, stream,
                     xprojT, wih_b, whh_b, weff_b, b_eff, enc_c,
                     h_ext, outs_e, bar);

  // logits[b*T+t][V] = outs @ W_final^T + b_final
  // (256x256 tile, 8 waves, BK=64, dbuf + counted vmcnt; k_tr folded into A staging)
  hipLaunchKernelGGL(k_gemm2, dim3(1000), dim3(512), 0, stream,
                     outs_e + 16384, wfin_b, logits, b_final);
}

// Round 14
// 745.260 us; speedup vs baseline: 1.0544x; 1.0544x over previous
//
#include <hip/hip_runtime.h>
#include <hip/hip_bf16.h>

// Dims
#define BB 32
#define TT 64
#define HH 512
#define EE 512
#define VV 32000

typedef float f32x4 __attribute__((ext_vector_type(4)));
typedef float f32x16 __attribute__((ext_vector_type(16)));
typedef __bf16 bf16x8 __attribute__((ext_vector_type(8)));
typedef unsigned short u16x8 __attribute__((ext_vector_type(8)));

static __device__ __forceinline__ unsigned short f2bf(float f) {
  unsigned int u = __builtin_bit_cast(unsigned int, f);
  u += 0x7fffu + ((u >> 16) & 1u);   // RNE; inputs are finite
  return (unsigned short)(u >> 16);
}

static __device__ __forceinline__ void gload16(const void* g, void* l) {
  __builtin_amdgcn_global_load_lds(
      (const __attribute__((address_space(1))) void*)g,
      (__attribute__((address_space(3))) void*)l, 16, 0, 0);
}

// ---- fp32 -> bf16 bulk convert (8 elems/thread) ----
__global__ __launch_bounds__(256) void k_cvt_bf16(const float* __restrict__ in,
                                                  unsigned short* __restrict__ out,
                                                  int n8) {
  int tid = blockIdx.x * 256 + threadIdx.x;
  if (tid >= n8) return;
  int idx = tid * 8;
  float4 a = *(const float4*)(in + idx);
  float4 b = *(const float4*)(in + idx + 4);
  u16x8 o;
  o[0] = f2bf(a.x); o[1] = f2bf(a.y); o[2] = f2bf(a.z); o[3] = f2bf(a.w);
  o[4] = f2bf(b.x); o[5] = f2bf(b.y); o[6] = f2bf(b.z); o[7] = f2bf(b.w);
  *(u16x8*)(out + idx) = o;
}

// ---- fp32 [K][M] -> bf16 [M][K] transpose-convert (32x32 tiles) ----
__global__ __launch_bounds__(256) void k_trcvt(const float* __restrict__ in,  // [512][512]
                                               unsigned short* __restrict__ out) {
  __shared__ float tile[32][33];
  const int tx = threadIdx.x & 31, ty = threadIdx.x >> 5;   // 32x8
  const int k0 = blockIdx.x * 32, m0 = blockIdx.y * 32;
#pragma unroll
  for (int r = 0; r < 4; ++r)
    tile[ty + r * 8][tx] = in[(size_t)(k0 + ty + r * 8) * 512 + m0 + tx];
  __syncthreads();
#pragma unroll
  for (int r = 0; r < 4; ++r)
    out[(size_t)(m0 + ty + r * 8) * 512 + k0 + tx] = f2bf(tile[tx][ty + r * 8]);
}

// ---- embedding gather -> bf16, layout [t*B+b][E] ----
__global__ __launch_bounds__(256) void k_emb(const int* __restrict__ seq,
                                             const float* __restrict__ emb,
                                             unsigned short* __restrict__ out) {
  int tid = blockIdx.x * 256 + threadIdx.x;   // 2048*512/8 = 131072 threads
  int idx = tid * 8;
  int m = idx >> 9;          // t*32 + b
  int e0 = idx & 511;
  int t = m >> 5, b = m & 31;
  int s = seq[b * TT + t];
  const float* src = emb + (size_t)s * EE + e0;
  float4 a = *(const float4*)(src);
  float4 c = *(const float4*)(src + 4);
  u16x8 o;
  o[0] = f2bf(a.x); o[1] = f2bf(a.y); o[2] = f2bf(a.z); o[3] = f2bf(a.w);
  o[4] = f2bf(c.x); o[5] = f2bf(c.y); o[6] = f2bf(c.z); o[7] = f2bf(c.w);
  *(u16x8*)(out + m * EE + e0) = o;
}

__global__ __launch_bounds__(256) void k_beff(const float* __restrict__ W_out,
                                              const float* __restrict__ b_in,
                                              const float* __restrict__ b_out,
                                              float* __restrict__ b_eff) {
  int i = blockIdx.x * 256 + threadIdx.x;
  if (i >= HH) return;
  float acc = b_out[i];
  for (int k = 0; k < HH; ++k) acc += W_out[i * 1024 + k] * b_in[k];
  b_eff[i] = acc;
}

// ---- bf16 MFMA GEMM (m97-style): C[M][N] = A[M][K]*Bm[N][K]^T (+biases,+addend) ----
// Used for the small GEMMs (weff, xproj). Linear LDS [128][32], gload_lds staging.
__global__ __launch_bounds__(256) void k_gemm(const unsigned short* __restrict__ A, int lda,
                                              const unsigned short* __restrict__ Bm, int ldb,
                                              float* __restrict__ C, int ldc,
                                              const float* __restrict__ bias1,
                                              const float* __restrict__ bias2,
                                              const float* __restrict__ biasR1,
                                              const float* __restrict__ biasR2,
                                              const float* __restrict__ Cadd, int ldadd,
                                              int K, int m_panels) {
  __shared__ unsigned short As[128 * 32];
  __shared__ unsigned short Bs[128 * 32];
  const int tx = threadIdx.x;
  const int lane = tx & 63, w = tx >> 6;
  const int wrow = (w >> 1) * 64, wcol = (w & 1) * 64;
  const int l15 = lane & 15, lk = lane >> 4;
  const int nb = gridDim.x;
  const int swz = (blockIdx.x & 7) * (nb >> 3) + (blockIdx.x >> 3);
  const int m0 = (swz % m_panels) * 128, n0 = (swz / m_panels) * 128;
  const int r_lane = lane >> 2;          // row within a 16-row chunk
  const int k_lane = (lane & 3) * 8;     // k element offset within BK=32
  f32x4 acc[4][4] = {};
  for (int k0 = 0; k0 < K; k0 += 32) {
#pragma unroll
    for (int h = 0; h < 2; ++h) {
      int r0 = w * 32 + h * 16;
      gload16(A + (size_t)(m0 + r0 + r_lane) * lda + k0 + k_lane, &As[r0 * 32]);
      gload16(Bm + (size_t)(n0 + r0 + r_lane) * ldb + k0 + k_lane, &Bs[r0 * 32]);
    }
    asm volatile("s_waitcnt vmcnt(0)" ::: "memory");
    __syncthreads();
    bf16x8 av[4], bv[4];
#pragma unroll
    for (int mi = 0; mi < 4; ++mi)
      av[mi] = __builtin_bit_cast(bf16x8, *(const int4*)(&As[(wrow + mi * 16 + l15) * 32 + lk * 8]));
#pragma unroll
    for (int ni = 0; ni < 4; ++ni)
      bv[ni] = __builtin_bit_cast(bf16x8, *(const int4*)(&Bs[(wcol + ni * 16 + l15) * 32 + lk * 8]));
#pragma unroll
    for (int mi = 0; mi < 4; ++mi)
#pragma unroll
      for (int ni = 0; ni < 4; ++ni)
        acc[mi][ni] = __builtin_amdgcn_mfma_f32_16x16x32_bf16(av[mi], bv[ni], acc[mi][ni], 0, 0, 0);
    __syncthreads();
  }
#pragma unroll
  for (int mi = 0; mi < 4; ++mi) {
#pragma unroll
    for (int ni = 0; ni < 4; ++ni) {
      int row = m0 + wrow + mi * 16 + lk * 4;
      int col = n0 + wcol + ni * 16 + l15;
      float bb = 0.f;
      if (bias1) bb += bias1[col];
      if (bias2) bb += bias2[col];
#pragma unroll
      for (int q = 0; q < 4; ++q) {
        float bR = 0.f;
        if (biasR1) bR += biasR1[row + q];
        if (biasR2) bR += biasR2[row + q];
        float ad = Cadd ? Cadd[(size_t)(row + q) * ldadd + col] : 0.f;
        C[(size_t)(row + q) * ldc + col] = acc[mi][ni][q] + bb + bR + ad;
      }
    }
  }
}

// ---- logits GEMM v2 (r12-proven): 128x128 tile, BK=64, dbuf LDS + counted vmcnt ----
// C[2048][32000] = A[2048][512] * B[32000][512]^T + biasN.
// gload_lds writes linearly; XOR swizzle applied to per-lane GLOBAL source chunk
// and to the ds_read byte address (both-sides rule). Loads for the next K-step
// stay in flight across the current step's MFMA (T3/T4: vmcnt(8), never 0 mid-loop).
__global__ __launch_bounds__(256) void k_gemm2(const unsigned short* __restrict__ A,
                                               const unsigned short* __restrict__ Bm,
                                               float* __restrict__ C,
                                               const float* __restrict__ biasN) {
  __shared__ unsigned short As[2][128 * 64];   // 2 x 16 KB
  __shared__ unsigned short Bs[2][128 * 64];   // 2 x 16 KB
  const int tx = threadIdx.x;
  const int lane = tx & 63, w = tx >> 6;
  const int wrow = (w >> 1) * 64, wcol = (w & 1) * 64;
  const int l15 = lane & 15, lk = lane >> 4;
  const int nb = gridDim.x;                 // 4000
  const int swz = (blockIdx.x & 7) * (nb >> 3) + (blockIdx.x >> 3);
  const int m0 = (swz & 15) * 128, n0 = (swz >> 4) * 128;
  const int lr = lane >> 3, lc = lane & 7;  // staging: row-in-8chunk, chunk idx
  f32x4 acc[4][4] = {};

  auto stage = [&](int buf, int k0) {       // 8 gload16 per wave
#pragma unroll
    for (int i = 0; i < 4; ++i) {
      int row = w * 32 + i * 8 + lr;
      int csw = lc ^ (row & 7);
      gload16(A + (size_t)(m0 + row) * 512 + k0 + csw * 8, &As[buf][(w * 32 + i * 8) * 64]);
    }
#pragma unroll
    for (int i = 0; i < 4; ++i) {
      int row = w * 32 + i * 8 + lr;
      int csw = lc ^ (row & 7);
      gload16(Bm + (size_t)(n0 + row) * 512 + k0 + csw * 8, &Bs[buf][(w * 32 + i * 8) * 64]);
    }
  };

  stage(0, 0);
  for (int ks = 0; ks < 8; ++ks) {
    const int cur = ks & 1;
    if (ks < 7) {
      stage(cur ^ 1, (ks + 1) * 64);
      asm volatile("s_waitcnt vmcnt(8)" ::: "memory");   // oldest 8 (cur buf) landed
    } else {
      asm volatile("s_waitcnt vmcnt(0)" ::: "memory");
    }
    __syncthreads();
    const char* Ab = (const char*)As[cur];
    const char* Bb = (const char*)Bs[cur];
#pragma unroll
    for (int kk = 0; kk < 2; ++kk) {        // two K32-chunks
      bf16x8 av[4], bv[4];
#pragma unroll
      for (int mi = 0; mi < 4; ++mi) {
        int row = wrow + mi * 16 + l15;
        int c = kk * 4 + lk;
        av[mi] = __builtin_bit_cast(bf16x8,
            *(const int4*)(Ab + row * 128 + ((c ^ (row & 7)) << 4)));
      }
#pragma unroll
      for (int ni = 0; ni < 4; ++ni) {
        int row = wcol + ni * 16 + l15;
        int c = kk * 4 + lk;
        bv[ni] = __builtin_bit_cast(bf16x8,
            *(const int4*)(Bb + row * 128 + ((c ^ (row & 7)) << 4)));
      }
#pragma unroll
      for (int mi = 0; mi < 4; ++mi)
#pragma unroll
        for (int ni = 0; ni < 4; ++ni)
          acc[mi][ni] = __builtin_amdgcn_mfma_f32_16x16x32_bf16(av[mi], bv[ni], acc[mi][ni], 0, 0, 0);
    }
    __syncthreads();   // all waves done reading buf[cur] before next stage overwrites it
  }
#pragma unroll
  for (int mi = 0; mi < 4; ++mi) {
#pragma unroll
    for (int ni = 0; ni < 4; ++ni) {
      int row = m0 + wrow + mi * 16 + lk * 4;
      int col = n0 + wcol + ni * 16 + l15;
      float bb = biasN[col];
#pragma unroll
      for (int q = 0; q < 4; ++q)
        __builtin_nontemporal_store(acc[mi][ni][q] + bb,
                                    &C[(size_t)(row + q) * 32000 + col]);
    }
  }
}

// ---- fence-free grid barrier for 64 blocks (r6-proven, WITH sleep) ----
static __device__ __forceinline__ void gbar(unsigned* __restrict__ bar, unsigned gen) {
  __syncthreads();
  if (threadIdx.x == 0) {
    asm volatile("s_waitcnt vmcnt(0)" ::: "memory");
    __hip_atomic_store(&bar[blockIdx.x], gen, __ATOMIC_RELAXED, __HIP_MEMORY_SCOPE_AGENT);
  }
  if (threadIdx.x < 64) {
    while (__hip_atomic_load(&bar[threadIdx.x], __ATOMIC_RELAXED, __HIP_MEMORY_SCOPE_AGENT) < gen)
      __builtin_amdgcn_s_sleep(1);
  }
  __syncthreads();
  asm volatile("" ::: "memory");   // keep data loads below the spin
}

// ---- persistent MFMA recurrence: 64 blocks x 256 threads (4 waves), r6-proven ----
__global__ __launch_bounds__(256, 1) void k_recur(
    const float* __restrict__ xprojT,       // [2048][2048] fp32 (incl. b_ih+b_hh)
    const unsigned short* __restrict__ wih_b,  // [2048][1024] bf16
    const unsigned short* __restrict__ whh_b,  // [2048][512] bf16
    const unsigned short* __restrict__ weff_b, // [512][512] bf16
    const float* __restrict__ b_eff,        // [512]
    const float* __restrict__ enc_c,        // [32][512] fp32
    unsigned short* __restrict__ h_ext,     // [65][32][512] bf16; slab 0 = bf16(enc_h)
    unsigned short* __restrict__ outs_ext,  // [65][32][512] bf16; slab 0 zeroed
    unsigned* __restrict__ bar)
{
  __shared__ int4 Abuf4[4096];             // A[32][1024] bf16, XOR-swizzled (64 KB)
  __shared__ float red[4][32][32];         // cross-wave K-partials (16 KB)
  char* Abuf = (char*)Abuf4;

  const int tx = threadIdx.x;
  const int bid = blockIdx.x;
  const int i0 = bid * 8;
  const int w = tx >> 6, l = tx & 63;
  const int jl = l & 31;                   // MFMA operand row (gate-row local / batch)
  const int kh = (l >> 5) * 8;             // k sub-offset within a K16 tile
  const int u = tx >> 5, b = tx & 31;      // activation mapping: unit u (0..7), batch b

  // ---- one-time: weights into registers ----
  bf16x8 wg[16];
  {
    const int jg = (jl >> 3) * 512 + i0 + (jl & 7);   // global gate row
#pragma unroll
    for (int r = 0; r < 16; ++r) {
      int k0 = (w * 16 + r) * 16 + kh;
      const unsigned short* src = (k0 < 512)
          ? wih_b + (size_t)jg * 1024 + 512 + k0      // feed half of W_ih
          : whh_b + (size_t)jg * 512 + (k0 - 512);    // W_hh
      wg[r] = __builtin_bit_cast(bf16x8, *(const int4*)src);
    }
  }
  bf16x8 we[8];
  {
    const int wr = (bid >> 2) * 32 + jl;              // W_eff row (unit group)
#pragma unroll
    for (int r = 0; r < 8; ++r) {
      int k0 = (w * 8 + r) * 16 + kh;
      we[r] = __builtin_bit_cast(bf16x8, *(const int4*)(weff_b + (size_t)wr * 512 + k0));
    }
  }
  float c_reg = enc_c[b * 512 + i0 + u];
  const float be = b_eff[i0 + u];

  // ---- block-wide stage helpers (r6) ----
  auto stage = [&](const unsigned short* __restrict__ src, int half) {
#pragma unroll
    for (int rnd = 0; rnd < 8; ++rnd) {
      int id = rnd * 256 + tx;
      int row = id >> 6, c16 = id & 63;
      int4 v = *(const int4*)(src + (size_t)row * 512 + c16 * 8);
      int byte = (row * 2048 + half * 1024 + c16 * 16) ^ ((row & 7) << 4);
      *(int4*)(Abuf + byte) = v;
    }
  };
  auto afrag = [&](int ktile) -> bf16x8 {   // ktile in K16 units over full K=1024
    int byte = (jl * 2048 + ktile * 32 + (l >> 5) * 16) ^ ((jl & 7) << 4);
    return __builtin_bit_cast(bf16x8, *(const int4*)(Abuf + byte));
  };

  // initial stage: feed slab 0 (zeros) + h slab 0 (enc_h)
  stage(outs_ext, 0);
  stage(h_ext, 1);
  __syncthreads();

  unsigned gen = 1;
  for (int t = 0; t < 64; ++t) {
    // ================= phase 1: gates -> h_t+1 =================
    float xp[4];
#pragma unroll
    for (int g = 0; g < 4; ++g)
      xp[g] = xprojT[(size_t)(g * 512 + i0 + u) * 2048 + t * 32 + b];
    f32x16 acc = {};
#pragma unroll
    for (int r = 0; r < 16; ++r)
      acc = __builtin_amdgcn_mfma_f32_32x32x16_bf16(wg[r], afrag(w * 16 + r), acc, 0, 0, 0);
#pragma unroll
    for (int reg = 0; reg < 16; ++reg) {
      int row = (reg & 3) + 8 * (reg >> 2) + 4 * (l >> 5);
      red[w][row][jl] = acc[reg];
    }
    __syncthreads();
    {
      float g4[4];
#pragma unroll
      for (int g = 0; g < 4; ++g)
        g4[g] = red[0][g * 8 + u][b] + red[1][g * 8 + u][b]
              + red[2][g * 8 + u][b] + red[3][g * 8 + u][b] + xp[g];
      float si = 1.f / (1.f + __expf(-g4[0]));
      float sf = 1.f / (1.f + __expf(-g4[1]));
      float so = 1.f / (1.f + __expf(-g4[3]));
      float cn = sf * c_reg + si * tanhf(g4[2]);
      c_reg = cn;
      unsigned hb = f2bf(so * tanhf(cn));
      unsigned other = (unsigned)__shfl_down((int)hb, 32);
      if ((u & 1) == 0) {
        unsigned* h32 = (unsigned*)(h_ext + (size_t)(t + 1) * 16384);
        __hip_atomic_store(&h32[b * 256 + bid * 4 + (u >> 1)], hb | (other << 16),
                           __ATOMIC_RELAXED, __HIP_MEMORY_SCOPE_AGENT);
      }
    }
    gbar(bar, gen++);   // h_t+1 visible device-wide

    // ================= phase 2: feed = tanh(W_eff h + b_eff) =================
    stage(h_ext + (size_t)(t + 1) * 16384, 1);
    __syncthreads();
    f32x16 acc2 = {};
#pragma unroll
    for (int r = 0; r < 8; ++r)
      acc2 = __builtin_amdgcn_mfma_f32_32x32x16_bf16(we[r], afrag(32 + w * 8 + r), acc2, 0, 0, 0);
#pragma unroll
    for (int reg = 0; reg < 16; ++reg) {
      int row = (reg & 3) + 8 * (reg >> 2) + 4 * (l >> 5);
      red[w][row][jl] = acc2[reg];
    }
    __syncthreads();
    {
      int row = (bid & 3) * 8 + u;
      float s = red[0][row][b] + red[1][row][b] + red[2][row][b] + red[3][row][b] + be;
      unsigned ob = f2bf(tanhf(s));
      unsigned other = (unsigned)__shfl_down((int)ob, 32);
      if ((u & 1) == 0) {
        unsigned* o32 = (unsigned*)(outs_ext + (size_t)(t + 1) * 16384);
        __hip_atomic_store(&o32[b * 256 + bid * 4 + (u >> 1)], ob | (other << 16),
                           __ATOMIC_RELAXED, __HIP_MEMORY_SCOPE_AGENT);
      }
    }
    gbar(bar, gen++);   // feed visible device-wide

    if (t < 63) {       // stage next step's feed
      stage(outs_ext + (size_t)(t + 1) * 16384, 0);
      __syncthreads();
    }
  }
}

// ---- outs bf16 [T][B][H] -> A_bt [(b*T+t)][H] bf16 (pure transpose copy) ----
__global__ __launch_bounds__(256) void k_tr(const unsigned short* __restrict__ outs,
                                            unsigned short* __restrict__ abt) {
  int tid = blockIdx.x * 256 + threadIdx.x;   // 131072 threads
  int idx = tid * 8;
  int m = idx >> 9;        // b*64 + t
  int h0 = idx & 511;
  int b = m >> 6, t = m & 63;
  *(u16x8*)(abt + m * 512 + h0) =
      *(const u16x8*)(outs + (size_t)(t * 32 + b) * 512 + h0);
}

extern "C" void kernel_launch(void* const* d_in, const int* in_sizes, int n_in,
                              void* d_out, int out_size, void* d_ws, size_t ws_size,
                              hipStream_t stream) {
  const int*   seq      = (const int*)d_in[0];
  // d_in[1] = encoder_outputs: attention scores are dead code -> unused
  const float* enc_h    = (const float*)d_in[2];
  const float* enc_c    = (const float*)d_in[3];
  const float* emb      = (const float*)d_in[4];
  const float* W_ih     = (const float*)d_in[5];
  const float* b_ih     = (const float*)d_in[6];
  const float* W_hh     = (const float*)d_in[7];
  const float* b_hh     = (const float*)d_in[8];
  const float* W_inp    = (const float*)d_in[9];
  const float* b_inp    = (const float*)d_in[10];
  const float* W_outp   = (const float*)d_in[11];
  const float* b_outp   = (const float*)d_in[12];
  const float* W_final  = (const float*)d_in[13];
  const float* b_final  = (const float*)d_in[14];
  float* logits = (float*)d_out;

  char* ws = (char*)d_ws;
  size_t off = 0;
  auto alloc = [&](size_t bytes) {
    char* p = ws + off;
    off += (bytes + 255) & ~(size_t)255;
    return p;
  };
  unsigned short* wih_b  = (unsigned short*)alloc((size_t)2048 * 1024 * 2);
  unsigned short* whh_b  = (unsigned short*)alloc((size_t)2048 * 512 * 2);
  unsigned short* wfin_b = (unsigned short*)alloc((size_t)VV * HH * 2);
  unsigned short* weff_b = (unsigned short*)alloc((size_t)512 * 512 * 2);
  unsigned short* wout_b = (unsigned short*)alloc((size_t)512 * 1024 * 2);
  unsigned short* win_t  = (unsigned short*)alloc((size_t)512 * 512 * 2);
  unsigned short* emb_b  = (unsigned short*)alloc((size_t)2048 * 512 * 2);
  float* xprojT = (float*)alloc((size_t)2048 * 2048 * 4);
  float* W_eff  = (float*)alloc((size_t)512 * 512 * 4);
  float* b_eff  = (float*)alloc((size_t)512 * 4);
  unsigned short* h_ext  = (unsigned short*)alloc((size_t)65 * 32 * 512 * 2);
  unsigned short* outs_e = (unsigned short*)alloc((size_t)65 * 32 * 512 * 2);
  unsigned short* abt = (unsigned short*)alloc((size_t)2048 * 512 * 2);
  unsigned* bar = (unsigned*)alloc(4096);

  // per-call init (graph-safe)
  hipMemsetAsync(bar, 0, 4096, stream);
  hipMemsetAsync(outs_e, 0, (size_t)32 * 512 * 2, stream);   // feed for t=0 (bf16 zero)

  hipLaunchKernelGGL(k_cvt_bf16, dim3(1024), dim3(256), 0, stream, W_ih, wih_b, 2048 * 1024 / 8);
  hipLaunchKernelGGL(k_cvt_bf16, dim3(512), dim3(256), 0, stream, W_hh, whh_b, 2048 * 512 / 8);
  hipLaunchKernelGGL(k_cvt_bf16, dim3(8000), dim3(256), 0, stream, W_final, wfin_b, VV * HH / 8);
  hipLaunchKernelGGL(k_cvt_bf16, dim3(8), dim3(256), 0, stream, enc_h, h_ext, 32 * 512 / 8);
  hipLaunchKernelGGL(k_cvt_bf16, dim3(256), dim3(256), 0, stream, W_outp, wout_b, 512 * 1024 / 8);
  hipLaunchKernelGGL(k_trcvt, dim3(16, 16), dim3(256), 0, stream, W_inp, win_t);
  hipLaunchKernelGGL(k_emb, dim3(512), dim3(256), 0, stream, seq, emb, emb_b);
  hipLaunchKernelGGL(k_beff, dim3(2), dim3(256), 0, stream, W_outp, b_inp, b_outp, b_eff);

  // W_eff = W_out[:, :H] @ W_in + W_out[:, H:]  via MFMA
  hipLaunchKernelGGL(k_gemm, dim3(16), dim3(256), 0, stream,
                     wout_b, 1024, win_t, 512, W_eff, 512,
                     (const float*)nullptr, (const float*)nullptr,
                     (const float*)nullptr, (const float*)nullptr,
                     W_outp + 512, 1024, 512, 4);
  hipLaunchKernelGGL(k_cvt_bf16, dim3(128), dim3(256), 0, stream, W_eff, weff_b, 512 * 512 / 8);

  // xprojT[j][t*32+b] = W_ih[:, :E] @ emb^T + (b_ih + b_hh) per-row
  hipLaunchKernelGGL(k_gemm, dim3(256), dim3(256), 0, stream,
                     wih_b, 1024, emb_b, 512, xprojT, 2048,
                     (const float*)nullptr, (const float*)nullptr, b_ih, b_hh,
                     (const float*)nullptr, 0, 512, 16);

  // persistent MFMA recurrence: 64 blocks, all 64 steps, 2 barriers each
  hipLaunchKernelGGL(k_recur, dim3(64), dim3(256), 0, stream,
                     xprojT, wih_b, whh_b, weff_b, b_eff, enc_c,
                     h_ext, outs_e, bar);

  hipLaunchKernelGGL(k_tr, dim3(512), dim3(256), 0, stream, outs_e + 16384, abt);
  // logits[b*T+t][V] = A_bt @ W_final^T + b_final  (128x128, BK=64, dbuf+counted vmcnt)
  hipLaunchKernelGGL(k_gemm2, dim3(4000), dim3(256), 0, stream,
                     abt, wfin_b, logits, b_final);
}